// Round 8
// baseline (472.918 us; speedup 1.0000x reference)
//
#include <hip/hip_runtime.h>
#include <cstddef>
#include <math.h>

// ---------------- problem constants ----------------
#define B_   2
#define L_   2048
#define D_   512
#define E_   768
static const size_t LL   = (size_t)L_ * L_;
static const size_t SLOT = (size_t)B_ * LL;

#define QK_N  ((size_t)B_ * L_ * D_)       // 2097152
#define G1_N  ((size_t)512 * 512)          // 262144
#define G_N   ((size_t)6 * G1_N)           // 1572864
#define U_N   ((size_t)6 * L_ * D_)        // 6291456
#define X_N   ((size_t)4096 * 768)         // 3145728
#define W_N   ((size_t)512 * 768)          // 393216

typedef unsigned short u16;
typedef __attribute__((ext_vector_type(8))) _Float16 half8;  // 8 f16 (4 VGPR)
typedef __attribute__((ext_vector_type(4))) float f32x4;

// ---------------- f16x2 split of fp32, scaled residual ------------------------
// f = h0 + h1/4096 + r2, |r2| <= |f|*2^-24.
__device__ __forceinline__ void split2(float f, u16& h0, u16& h1) {
    _Float16 a = (_Float16)f;
    _Float16 b = (_Float16)((f - (float)a) * 4096.0f);
    h0 = __builtin_bit_cast(u16, a);
    h1 = __builtin_bit_cast(u16, b);
}

// ============ async global->LDS staging helpers ===============================
typedef const __attribute__((address_space(1))) void gas_void;
typedef __attribute__((address_space(3))) void las_void;

__device__ __forceinline__ void gload16(const u16* g, u16* l) {
    __builtin_amdgcn_global_load_lds((gas_void*)g, (las_void*)l, 16, 0, 0);
}

// ============ 128x64-tile MK PROM core (k_gram, k_u) — r3-proven ==============
// 4 waves as 2x2 of 64x32 quadrants, BK=32, fp64 promote per step. 24 KB LDS
// single-buffer, 2 barriers/step: high occupancy (grid-limited kernels) beats
// deeper scheduling here (r6 post-mortem: 48 KB cv variant lost ~20 µs).
__device__ __forceinline__ void gemm12864p(const u16* __restrict__ Ap, size_t Aps, int lda,
                                           const u16* __restrict__ Bp, size_t Bps, int ldb,
                                           int K, int m0, int n0, int tid,
                                           double outv[4][2][4]) {
    __shared__ u16 SA[2][128][32], SB[2][64][32];    // 24 KB
    f32x4 accH[4][2], accM[4][2];
#pragma unroll
    for (int i = 0; i < 4; ++i)
#pragma unroll
        for (int j = 0; j < 2; ++j) {
            accH[i][j] = (f32x4){0.f, 0.f, 0.f, 0.f};
            accM[i][j] = (f32x4){0.f, 0.f, 0.f, 0.f};
        }
    double accD[4][2][4] = {};
    int lane = tid & 63, w = tid >> 6;
    int wm = (w & 1) << 6, wn = (w >> 1) << 5;       // 64x32 wave quadrant
    int fr = lane & 15, ko8 = lane >> 4;             // k-chunk 0..3

    int rbA0 = (w << 5), rbA1 = (w << 5) + 16;       // A: two 16-row slabs/wave
    int rowA0 = rbA0 + (lane >> 2), rowA1 = rbA1 + (lane >> 2);
    int chA0 = (lane & 3) ^ ((rowA0 >> 1) & 3);
    int chA1 = (lane & 3) ^ ((rowA1 >> 1) & 3);
    int rbB = (w << 4);                              // B: one 16-row slab/wave
    int rowB = rbB + (lane >> 2);
    int chB = (lane & 3) ^ ((rowB >> 1) & 3);

    int nstep = K >> 5;
    for (int s = 0; s < nstep; ++s) {
        int k0 = s << 5;
#pragma unroll
        for (int sp = 0; sp < 2; ++sp) {
            gload16(Ap + (size_t)sp * Aps + (size_t)(m0 + rowA0) * lda + k0 + (chA0 << 3),
                    &SA[sp][rbA0][0]);
            gload16(Ap + (size_t)sp * Aps + (size_t)(m0 + rowA1) * lda + k0 + (chA1 << 3),
                    &SA[sp][rbA1][0]);
            gload16(Bp + (size_t)sp * Bps + (size_t)(n0 + rowB) * ldb + k0 + (chB << 3),
                    &SB[sp][rbB][0]);
        }
        __syncthreads();                             // drains vmcnt -> LDS valid
        half8 a[4][2], b[2][2];
#pragma unroll
        for (int f = 0; f < 4; ++f) {
            int ra = wm + (f << 4) + fr;
            int ca = (ko8 ^ ((ra >> 1) & 3)) << 3;   // matching read-side swizzle
#pragma unroll
            for (int sp = 0; sp < 2; ++sp)
                a[f][sp] = *reinterpret_cast<const half8*>(&SA[sp][ra][ca]);
        }
#pragma unroll
        for (int f = 0; f < 2; ++f) {
            int rbn = wn + (f << 4) + fr;
            int cb = (ko8 ^ ((rbn >> 1) & 3)) << 3;
#pragma unroll
            for (int sp = 0; sp < 2; ++sp)
                b[f][sp] = *reinterpret_cast<const half8*>(&SB[sp][rbn][cb]);
        }
#pragma unroll
        for (int fi = 0; fi < 4; ++fi)
#pragma unroll
            for (int fj = 0; fj < 2; ++fj) {
                accH[fi][fj] = __builtin_amdgcn_mfma_f32_16x16x32_f16(a[fi][0], b[fj][0], accH[fi][fj], 0, 0, 0);
                accM[fi][fj] = __builtin_amdgcn_mfma_f32_16x16x32_f16(a[fi][0], b[fj][1], accM[fi][fj], 0, 0, 0);
                accM[fi][fj] = __builtin_amdgcn_mfma_f32_16x16x32_f16(a[fi][1], b[fj][0], accM[fi][fj], 0, 0, 0);
            }
        __syncthreads();                             // reads done before overwrite
#pragma unroll
        for (int fi = 0; fi < 4; ++fi)
#pragma unroll
            for (int fj = 0; fj < 2; ++fj) {
#pragma unroll
                for (int r = 0; r < 4; ++r) accD[fi][fj][r] += (double)accH[fi][fj][r];
                accH[fi][fj] = (f32x4){0.f, 0.f, 0.f, 0.f};
            }
    }
    const double S1 = 1.0 / 4096.0;
#pragma unroll
    for (int fi = 0; fi < 4; ++fi)
#pragma unroll
        for (int fj = 0; fj < 2; ++fj)
#pragma unroll
            for (int r = 0; r < 4; ++r)
                outv[fi][fj][r] = accD[fi][fj][r] + (double)accM[fi][fj][r] * S1;
}

// ============ counted-vmcnt 128x128 MK core (k_proj, k_scores) — r6-proven ====
// 256 thr / 4 waves / 64x64 per wave / 2 blocks/CU; LDS ping-pong + counted
// vmcnt with raw barriers: stage K-step s+1 (8 loads/wave), s_waitcnt vmcnt(8)
// waits only for the OLDEST 8 (buf cur, staged a full compute-phase ago).
// Invariant: every wave vmcnt's BEFORE s_barrier -> at barrier-exit all waves'
// cur-buffer loads landed. lgkmcnt(0) before the 2nd barrier pins ds_reads
// ahead of next overwrite. Bit-identical numerics (verified absmax 0.0, r6).
__device__ __forceinline__ void gemm128cv(const u16* __restrict__ Ap, size_t Aps, int lda,
                                          const u16* __restrict__ Bp, size_t Bps, int ldb,
                                          int K, int m0, int n0, int tid,
                                          float* __restrict__ out, int ldo) {
    __shared__ u16 SA[2][2][128][32], SB[2][2][128][32];   // 64 KB
    f32x4 accH[4][4], accM[4][4];
#pragma unroll
    for (int i = 0; i < 4; ++i)
#pragma unroll
        for (int j = 0; j < 4; ++j) {
            accH[i][j] = (f32x4){0.f, 0.f, 0.f, 0.f};
            accM[i][j] = (f32x4){0.f, 0.f, 0.f, 0.f};
        }
    int lane = tid & 63, w = tid >> 6;
    int wm = (w & 1) << 6, wn = (w >> 1) << 6;       // 64x64 wave quadrant
    int fr = lane & 15, ko8 = lane >> 4;             // k-chunk 0..3

    int rb0 = (w << 5), rb1 = rb0 + 16;              // two 16-row slabs per wave
    int row0 = rb0 + (lane >> 2), row1 = rb1 + (lane >> 2);
    int ch0 = (lane & 3) ^ ((row0 >> 1) & 3);        // inverse-swizzled source
    int ch1 = (lane & 3) ^ ((row1 >> 1) & 3);

#define STG128(buf, k0)                                                                   \
    {                                                                                     \
        _Pragma("unroll")                                                                 \
        for (int sp = 0; sp < 2; ++sp) {                                                  \
            gload16(Ap + (size_t)sp * Aps + (size_t)(m0 + row0) * lda + (k0) + (ch0 << 3),\
                    &SA[buf][sp][rb0][0]);                                                \
            gload16(Ap + (size_t)sp * Aps + (size_t)(m0 + row1) * lda + (k0) + (ch1 << 3),\
                    &SA[buf][sp][rb1][0]);                                                \
            gload16(Bp + (size_t)sp * Bps + (size_t)(n0 + row0) * ldb + (k0) + (ch0 << 3),\
                    &SB[buf][sp][rb0][0]);                                                \
            gload16(Bp + (size_t)sp * Bps + (size_t)(n0 + row1) * ldb + (k0) + (ch1 << 3),\
                    &SB[buf][sp][rb1][0]);                                                \
        }                                                                                 \
    }

    STG128(0, 0);                                    // 8 loads in flight; no drain
    int nstep = K >> 5;
    for (int s = 0; s < nstep; ++s) {
        int cur = s & 1;
        if (s + 1 < nstep) {
            STG128(cur ^ 1, (s + 1) << 5);           // 16 in flight
            asm volatile("s_waitcnt vmcnt(8)" ::: "memory");   // oldest 8 (cur) landed
        } else {
            asm volatile("s_waitcnt vmcnt(0)" ::: "memory");
        }
        __builtin_amdgcn_s_barrier();                // raw: no vmcnt drain
        asm volatile("" ::: "memory");               // pin ds_reads below barrier
        half8 a[4][2], b[4][2];
#pragma unroll
        for (int f = 0; f < 4; ++f) {
            int ra = wm + (f << 4) + fr;
            int rbn = wn + (f << 4) + fr;
            int ca = (ko8 ^ ((ra >> 1) & 3)) << 3;   // matching read-side swizzle
            int cb = (ko8 ^ ((rbn >> 1) & 3)) << 3;
#pragma unroll
            for (int sp = 0; sp < 2; ++sp) {
                a[f][sp] = *reinterpret_cast<const half8*>(&SA[cur][sp][ra][ca]);
                b[f][sp] = *reinterpret_cast<const half8*>(&SB[cur][sp][rbn][cb]);
            }
        }
        __builtin_amdgcn_s_setprio(1);
#pragma unroll
        for (int fi = 0; fi < 4; ++fi)
#pragma unroll
            for (int fj = 0; fj < 4; ++fj) {
                accH[fi][fj] = __builtin_amdgcn_mfma_f32_16x16x32_f16(a[fi][0], b[fj][0], accH[fi][fj], 0, 0, 0);
                accM[fi][fj] = __builtin_amdgcn_mfma_f32_16x16x32_f16(a[fi][0], b[fj][1], accM[fi][fj], 0, 0, 0);
                accM[fi][fj] = __builtin_amdgcn_mfma_f32_16x16x32_f16(a[fi][1], b[fj][0], accM[fi][fj], 0, 0, 0);
            }
        __builtin_amdgcn_s_setprio(0);
        asm volatile("s_waitcnt lgkmcnt(0)" ::: "memory");   // all ds_reads retired
        __builtin_amdgcn_s_barrier();                // reads done before overwrite
    }
#undef STG128
    const double S1 = 1.0 / 4096.0;
    int col = lane & 15, rbase = (lane >> 4) << 2;
#pragma unroll
    for (int fi = 0; fi < 4; ++fi)
#pragma unroll
        for (int fj = 0; fj < 4; ++fj)
#pragma unroll
            for (int r = 0; r < 4; ++r) {
                int mm = m0 + wm + (fi << 4) + rbase + r;
                int nn = n0 + wn + (fj << 4) + col;
                out[(size_t)mm * ldo + nn] =
                    (float)((double)accH[fi][fj][r] + (double)accM[fi][fj][r] * S1);
            }
}

// ============ prep: RoPE trig table + input f16x2 split (merged launch) =======
__global__ __launch_bounds__(256) void k_prep(const float* __restrict__ x,
                                              const float* __restrict__ Wq,
                                              const float* __restrict__ Wk,
                                              u16* __restrict__ xP,
                                              u16* __restrict__ WP,
                                              double* __restrict__ tg) {
    int bx = blockIdx.x;
    if (bx < L_) {
        int l = bx, j = threadIdx.x;
        double e = (double)j * (1.0 / 256.0);
        double inv = pow(10000.0, -e);
        double ang = (double)l * inv;
        tg[(size_t)l * 512 + j] = cos(ang);
        tg[(size_t)l * 512 + 256 + j] = sin(ang);
        return;
    }
    size_t gid = (size_t)(bx - L_) * 256 + threadIdx.x;
    const size_t XH = X_N / 2, WH = W_N / 2;
    const float* src; u16* dst; size_t pn, off;
    if (gid < XH)            { src = x  + 2 * gid;              dst = xP;            pn = X_N; off = 2 * gid; }
    else if (gid < XH + WH)  { size_t g = gid - XH;      src = Wq + 2 * g; dst = WP;            pn = W_N; off = 2 * g; }
    else                     { size_t g = gid - XH - WH; src = Wk + 2 * g; dst = WP + 2 * W_N;  pn = W_N; off = 2 * g; }
    float2 v = *reinterpret_cast<const float2*>(src);
    u16 a0, a1, b0, b1;
    split2(v.x, a0, a1);
    split2(v.y, b0, b1);
    *reinterpret_cast<unsigned*>(dst + off)      = (unsigned)a0 | ((unsigned)b0 << 16);
    *reinterpret_cast<unsigned*>(dst + pn + off) = (unsigned)a1 | ((unsigned)b1 << 16);
}

// ============ k_proj: 128-tile plane GEMM (fp32 H acc — O(1) magnitudes) ======
__global__ __launch_bounds__(256, 2) void k_proj(const u16* __restrict__ xP,
                                                 const u16* __restrict__ WP,
                                                 float* __restrict__ qraw,
                                                 float* __restrict__ kraw) {
    int z = blockIdx.z;
    float* out = z ? kraw : qraw;
    const u16* Bp = WP + (size_t)z * 2 * W_N;
    gemm128cv(xP, X_N, E_, Bp, W_N, E_, E_,
              blockIdx.y * 128, blockIdx.x * 128, threadIdx.x, out, D_);
}

// ============ LayerNorm + RoPE (fp64) -> f16x2 planes, q&k in parallel ========
__global__ __launch_bounds__(256) void k_lnrope(const float* __restrict__ qraw,
                                                const float* __restrict__ kraw,
                                                const double* __restrict__ tg,
                                                const float* __restrict__ qg, const float* __restrict__ qb,
                                                const float* __restrict__ kg, const float* __restrict__ kb,
                                                u16* __restrict__ qP, u16* __restrict__ kP) {
    int row = blockIdx.x;           // b*2048 + l
    int l = row & (L_ - 1);
    int tid = threadIdx.x;
    int half = tid >> 7, t = tid & 127;      // half 0 -> q, half 1 -> k
    __shared__ double nrow[2][D_];
    __shared__ double red[8];
    __shared__ double cs_[256], sn_[256];
    {
        int j = tid & 255;
        if (tid < 256) { cs_[j] = tg[(size_t)l * 512 + j]; sn_[j] = tg[(size_t)l * 512 + 256 + j]; }
    }
    const float* rp = (half ? kraw : qraw) + (size_t)row * D_;
    const float* g  = half ? kg : qg;
    const float* bt = half ? kb : qb;
    u16* P = half ? kP : qP;
    float4 v = reinterpret_cast<const float4*>(rp)[t];
    double vv[4] = {(double)v.x, (double)v.y, (double)v.z, (double)v.w};
    double s = vv[0] + vv[1] + vv[2] + vv[3];
    double s2 = vv[0]*vv[0] + vv[1]*vv[1] + vv[2]*vv[2] + vv[3]*vv[3];
    for (int off = 32; off; off >>= 1) { s += __shfl_xor(s, off); s2 += __shfl_xor(s2, off); }
    int wv = tid >> 6;                       // waves 0,1 -> half 0; 2,3 -> half 1
    if ((tid & 63) == 0) { red[wv * 2] = s; red[wv * 2 + 1] = s2; }
    __syncthreads();
    double mu  = (red[half * 4 + 0] + red[half * 4 + 2]) * (1.0 / D_);
    double var = (red[half * 4 + 1] + red[half * 4 + 3]) * (1.0 / D_) - mu * mu;
    double rs = rsqrt(var + 1e-5);
    int d0 = t * 4;
    double o[4];
#pragma unroll
    for (int c = 0; c < 4; ++c) {
        int d = d0 + c;
        o[c] = (vv[c] - mu) * rs * (double)g[d] + (double)bt[d];
    }
#pragma unroll
    for (int c = 0; c < 4; ++c) nrow[half][d0 + c] = o[c];
    __syncthreads();
    u16 h[2][4];
#pragma unroll
    for (int c = 0; c < 4; ++c) {
        int d = d0 + c;
        double rot = (d < 256) ? -nrow[half][d + 256] : nrow[half][d - 256];
        float ov = (float)(nrow[half][d] * cs_[d & 255] + rot * sn_[d & 255]);
        split2(ov, h[0][c], h[1][c]);
    }
    size_t off = (size_t)row * D_ + d0;
#pragma unroll
    for (int sp = 0; sp < 2; ++sp)
        *reinterpret_cast<ushort4*>(P + sp * QK_N + off) = make_ushort4(h[sp][0], h[sp][1], h[sp][2], h[sp][3]);
}

// ============ transpose q/k planes -> [d][l] layout (for MK-layout gram) ======
__global__ __launch_bounds__(256) void k_qkT(const u16* __restrict__ qP,
                                             const u16* __restrict__ kP,
                                             u16* __restrict__ qPT,
                                             u16* __restrict__ kPT) {
    __shared__ u16 T[64][72];
    int z = blockIdx.z;
    int b = z & 1, sp = (z >> 1) & 1, tn = z >> 2;
    const u16* src = (tn ? kP : qP) + (size_t)sp * QK_N + (size_t)b * L_ * D_;
    u16* dst       = (tn ? kPT : qPT) + (size_t)sp * QK_N + (size_t)b * D_ * L_;
    int l0 = blockIdx.x * 64, d0 = blockIdx.y * 64;
    int tid = threadIdx.x;
#pragma unroll
    for (int i = 0; i < 2; ++i) {
        int idx = tid + i * 256;
        int lr = idx >> 3, dc8 = (idx & 7) << 3;
        *reinterpret_cast<uint4*>(&T[lr][dc8]) =
            *reinterpret_cast<const uint4*>(&src[(size_t)(l0 + lr) * D_ + d0 + dc8]);
    }
    __syncthreads();
#pragma unroll
    for (int i = 0; i < 2; ++i) {
        int idx = tid + i * 256;
        int dr = idx >> 3, lc8 = (idx & 7) << 3;
        u16 tmp[8];
#pragma unroll
        for (int c = 0; c < 8; ++c) tmp[c] = T[lc8 + c][dr];
        *reinterpret_cast<uint4*>(&dst[(size_t)(d0 + dr) * L_ + l0 + lc8]) =
            *reinterpret_cast<const uint4*>(tmp);
    }
}

// ============ Gram split-K=2: transposed planes -> fp32 partials (PROM) =======
__global__ __launch_bounds__(256, 2) void k_gram(const u16* __restrict__ qPT,
                                                 const u16* __restrict__ kPT,
                                                 float* __restrict__ Gpart) {
    int zz = blockIdx.z, half = zz & 1, z = zz >> 1;
    int b = z / 3, m = z % 3;
    const u16* A  = ((m == 2) ? qPT : kPT) + (size_t)b * D_ * L_ + (size_t)half * (L_ / 2);
    const u16* Bp = ((m == 0) ? kPT : qPT) + (size_t)b * D_ * L_ + (size_t)half * (L_ / 2);
    int m0 = blockIdx.y * 128, n0 = blockIdx.x * 64;
    double ov[4][2][4];
    gemm12864p(A, QK_N, L_, Bp, QK_N, L_, L_ / 2, m0, n0, threadIdx.x, ov);
    float* Gg = Gpart + (size_t)half * G_N + (size_t)z * G1_N;
    int lane = threadIdx.x & 63, w = threadIdx.x >> 6;
    int wm = (w & 1) << 6, wn = (w >> 1) << 5;
    int col = lane & 15, rbase = (lane >> 4) << 2;
#pragma unroll
    for (int fi = 0; fi < 4; ++fi)
#pragma unroll
        for (int fj = 0; fj < 2; ++fj)
#pragma unroll
            for (int r = 0; r < 4; ++r) {
                int mm = m0 + wm + fi * 16 + rbase + r;
                int nn = n0 + wn + fj * 16 + col;
                Gg[(size_t)mm * 512 + nn] = (float)ov[fi][fj][r];
            }
}

// ============ sum partials + TRANSPOSE + split into G^T planes ================
__global__ __launch_bounds__(256) void k_gsplitT(const float* __restrict__ Gpart,
                                                 u16* __restrict__ GPT) {
    __shared__ float T[64][65];
    int z = blockIdx.z, d0 = blockIdx.y * 64, e0 = blockIdx.x * 64;
    const float* Ga = Gpart + (size_t)z * G1_N;
    const float* Gb = Ga + G_N;
    int tid = threadIdx.x;
#pragma unroll
    for (int i = 0; i < 16; ++i) {
        int idx = tid + i * 256;
        int r = idx >> 6, c = idx & 63;
        size_t o = (size_t)(d0 + r) * 512 + e0 + c;
        T[r][c] = Ga[o] + Gb[o];
    }
    __syncthreads();
    u16* Gz = GPT + (size_t)z * G1_N;
#pragma unroll
    for (int i = 0; i < 16; ++i) {
        int idx = tid + i * 256;
        int er = idx >> 6, dc = idx & 63;
        u16 h0, h1; split2(T[dc][er], h0, h1);
        size_t o = (size_t)(e0 + er) * 512 + d0 + dc;
        Gz[o] = h0; Gz[G_N + o] = h1;
    }
}

// ============ U = {q,q,k} @ G : planes -> U planes (PROM, 128x64 core) ========
__global__ __launch_bounds__(256, 2) void k_u(const u16* __restrict__ qP,
                                              const u16* __restrict__ kP,
                                              const u16* __restrict__ GPT,
                                              u16* __restrict__ UP) {
    int z = blockIdx.z, b = z / 3, m = z % 3;
    const u16* A  = ((m == 2) ? kP : qP) + (size_t)b * L_ * D_;
    const u16* Bp = GPT + (size_t)z * G1_N;
    int m0 = blockIdx.y * 128, n0 = blockIdx.x * 64;
    double ov[4][2][4];
    gemm12864p(A, QK_N, D_, Bp, G_N, 512, D_, m0, n0, threadIdx.x, ov);
    int lane = threadIdx.x & 63, w = threadIdx.x >> 6;
    int wm = (w & 1) << 6, wn = (w >> 1) << 5;
    int col = lane & 15, rbase = (lane >> 4) << 2;
#pragma unroll
    for (int fi = 0; fi < 4; ++fi)
#pragma unroll
        for (int fj = 0; fj < 2; ++fj)
#pragma unroll
            for (int r = 0; r < 4; ++r) {
                float uf = (float)ov[fi][fj][r];
                int mm = m0 + wm + fi * 16 + rbase + r;
                int nn = n0 + wn + fj * 16 + col;
                size_t off = (size_t)z * ((size_t)L_ * D_) + (size_t)mm * D_ + nn;
                u16 h0, h1; split2(uf, h0, h1);
                UP[off] = h0; UP[U_N + off] = h1;
            }
}

// ============ scores = U @ {q,k,k}^T (fp32 H acc, 128-tile cv core) ===========
__global__ __launch_bounds__(256, 2) void k_scores(const u16* __restrict__ qP,
                                                   const u16* __restrict__ kP,
                                                   const u16* __restrict__ UP,
                                                   float* __restrict__ out) {
    int z = blockIdx.z, b = z / 3, m = z % 3;
    const u16* A  = UP + (size_t)z * ((size_t)L_ * D_);
    const u16* Bp = ((m == 0) ? qP : kP) + (size_t)b * L_ * D_;
    float* Co = out + (size_t)(1 + m) * SLOT + (size_t)b * LL;
    gemm128cv(A, U_N, D_, Bp, QK_N, D_, D_,
              blockIdx.y * 128, blockIdx.x * 128, threadIdx.x, Co, L_);
}

// ============ entmax-1.5 (slots 1-3): fp32, 9 bisect + 3 Newton ===============
__global__ __launch_bounds__(256) void k_entmax(float* __restrict__ base, int nrows,
                                                const float* __restrict__ wC,
                                                const float* __restrict__ wF,
                                                const float* __restrict__ wS) {
    int tid = threadIdx.x;
    int lane = tid & 63;
    int r = blockIdx.x * 4 + (tid >> 6);
    if (r >= nrows) return;
    int m = r >> 12;                 // 4096 rows per matrix
    const float* wp = (m == 0) ? wC : (m == 1) ? wF : wS;
    float hw = (float)(1.0 / (1.0 + exp(-(double)wp[0])));   // 0.5 * w
    float* row = base + (size_t)r * L_;
    float v[32];
    float mx = -3.4e38f;
#pragma unroll
    for (int j = 0; j < 32; ++j) {
        v[j] = row[lane + (j << 6)];
        mx = fmaxf(mx, v[j]);
    }
    for (int off = 32; off; off >>= 1) mx = fmaxf(mx, __shfl_xor(mx, off));
    float z[32];
#pragma unroll
    for (int j = 0; j < 32; ++j) z[j] = hw * (v[j] - mx);
    float lo = -1.0f, hi = 0.0f;
    for (int it = 0; it < 9; ++it) {
        float tau = 0.5f * (lo + hi);
        float ssum = 0.0f;
#pragma unroll
        for (int j = 0; j < 32; ++j) {
            float t = fmaxf(z[j] - tau, 0.0f);
            ssum = fmaf(t, t, ssum);
        }
        for (int off = 32; off; off >>= 1) ssum += __shfl_xor(ssum, off);
        if (ssum >= 1.0f) lo = tau; else hi = tau;
    }
    float tau = lo;   // f(lo) >= 1; Newton on convex f approaches root from left
    for (int it = 0; it < 3; ++it) {
        float s1 = 0.0f, s2 = 0.0f;
#pragma unroll
        for (int j = 0; j < 32; ++j) {
            float t = fmaxf(z[j] - tau, 0.0f);
            s1 += t;
            s2 = fmaf(t, t, s2);
        }
        for (int off = 32; off; off >>= 1) { s1 += __shfl_xor(s1, off); s2 += __shfl_xor(s2, off); }
        float denom = 2.0f * s1;
        if (denom > 1e-30f) tau += fmaxf((s2 - 1.0f) / denom, 0.0f);
    }
#pragma unroll
    for (int j = 0; j < 32; ++j) {
        float t = fmaxf(z[j] - tau, 0.0f);
        row[lane + (j << 6)] = fminf(t * t, 1.0f - 1e-6f);
    }
}

// ============ column sums: partials (deterministic, parallel) =================
__global__ __launch_bounds__(256) void k_colsum(const float* __restrict__ out,
                                                double* __restrict__ part) {
    int bz = blockIdx.z, which = bz >> 1, b = bz & 1;
    const float* mat = out + (size_t)(which ? 3 : 1) * SLOT + (size_t)b * LL;
    int j = blockIdx.x * 256 + threadIdx.x;
    int r0 = blockIdx.y * 128;
    double s = 0.0;
#pragma unroll 8
    for (int r = 0; r < 128; ++r) s += (double)mat[(size_t)(r0 + r) * L_ + j];
    part[((size_t)bz * 16 + blockIdx.y) * L_ + j] = s;
}

__global__ __launch_bounds__(256) void k_colred(const double* __restrict__ part,
                                                double* __restrict__ csC,
                                                double* __restrict__ csS) {
    int g = blockIdx.x * 256 + threadIdx.x;   // 0..8191 = bz*2048 + j
    int bz = g >> 11, j = g & (L_ - 1);
    int which = bz >> 1, b = bz & 1;
    double s = 0.0;
#pragma unroll
    for (int c = 0; c < 16; ++c) s += part[((size_t)bz * 16 + c) * L_ + j];
    (which ? csS : csC)[b * L_ + j] = s;
}

// ============ fused finalize + entmax(H): one block per row ===================
__global__ __launch_bounds__(256) void k_fin2(float* __restrict__ out,
                                              const double* __restrict__ csC,
                                              const double* __restrict__ csS) {
    int row = blockIdx.x;               // b*2048 + i
    int i = row & (L_ - 1), b = row >> 11;
    size_t ro = (size_t)row * L_;
    float* H  = out + ro;
    float* pC = out + SLOT + ro;
    float* pF = out + 2 * SLOT + ro;
    float* pS = out + 3 * SLOT + ro;
    const double* cc = csC + b * L_;
    const double* cs = csS + b * L_;
    int tid = threadIdx.x, lane = tid & 63, wv = tid >> 6;
    __shared__ float red[4], red2[4];
    const double A1 = 1.0 - 2e-6;
    float h[8];
    float mx = -3.4e38f;
#pragma unroll
    for (int c = 0; c < 8; ++c) {
        int j = (c << 8) + tid;
        double cv = (double)pC[j] * rsqrt(cc[j] + 1e-6);
        double fv = (double)pF[j];
        double sv = (double)pS[j] * rsqrt(cs[j] + 1e-6);
        cv = fmax(A1 * cv + 1e-6, 1e-6);
        fv = fmax(A1 * fv + 1e-6, 1e-6);
        sv = fmax(A1 * sv + 1e-6, 1e-6);
        pC[j] = (float)cv; pF[j] = (float)fv; pS[j] = (float)sv;
        h[c] = (j == i) ? -1e9f : logf((float)(cv * fv * sv)) * (1.0f / 3.0f);
        mx = fmaxf(mx, h[c]);
    }
    for (int off = 32; off; off >>= 1) mx = fmaxf(mx, __shfl_xor(mx, off));
    if (lane == 0) red[wv] = mx;
    __syncthreads();
    mx = fmaxf(fmaxf(red[0], red[1]), fmaxf(red[2], red[3]));
    __syncthreads();
    float z[8];
#pragma unroll
    for (int c = 0; c < 8; ++c) z[c] = 0.5f * (h[c] - mx);
    float lo = -1.0f, hi = 0.0f;
    for (int it = 0; it < 9; ++it) {
        float tau = 0.5f * (lo + hi);
        float ssum = 0.0f;
#pragma unroll
        for (int c = 0; c < 8; ++c) {
            float t = fmaxf(z[c] - tau, 0.0f);
            ssum = fmaf(t, t, ssum);
        }
        for (int off = 32; off; off >>= 1) ssum += __shfl_xor(ssum, off);
        if (lane == 0) red[wv] = ssum;
        __syncthreads();
        ssum = red[0] + red[1] + red[2] + red[3];
        __syncthreads();
        if (ssum >= 1.0f) lo = tau; else hi = tau;
    }
    float tau = lo;
    for (int it = 0; it < 3; ++it) {
        float s1 = 0.0f, s2 = 0.0f;
#pragma unroll
        for (int c = 0; c < 8; ++c) {
            float t = fmaxf(z[c] - tau, 0.0f);
            s1 += t;
            s2 = fmaf(t, t, s2);
        }
        for (int off = 32; off; off >>= 1) { s1 += __shfl_xor(s1, off); s2 += __shfl_xor(s2, off); }
        if (lane == 0) { red[wv] = s1; red2[wv] = s2; }
        __syncthreads();
        s1 = red[0] + red[1] + red[2] + red[3];
        s2 = red2[0] + red2[1] + red2[2] + red2[3];
        __syncthreads();
        float denom = 2.0f * s1;
        if (denom > 1e-30f) tau += fmaxf((s2 - 1.0f) / denom, 0.0f);
    }
#pragma unroll
    for (int c = 0; c < 8; ++c) {
        float t = fmaxf(z[c] - tau, 0.0f);
        H[(c << 8) + tid] = t * t;
    }
}

// ============ launch ==========================================================
extern "C" void kernel_launch(void* const* d_in, const int* in_sizes, int n_in,
                              void* d_out, int out_size, void* d_ws, size_t ws_size,
                              hipStream_t stream) {
    const float* x  = (const float*)d_in[0];
    const float* Wq = (const float*)d_in[1];
    const float* Wk = (const float*)d_in[2];
    const float* qg = (const float*)d_in[3];
    const float* qb = (const float*)d_in[4];
    const float* kg = (const float*)d_in[5];
    const float* kb = (const float*)d_in[6];
    const float* wC = (const float*)d_in[7];
    const float* wF = (const float*)d_in[8];
    const float* wS = (const float*)d_in[9];
    float* out = (float*)d_out;

    // workspace: region boundaries identical to proven round-11..14 layout.
    char* wsb = (char*)d_ws;
    u16*    UP   = (u16*)wsb;
    float*  qraw = (float*)wsb;
    float*  kraw = qraw + QK_N;
    u16*    qPT  = (u16*)wsb;
    u16*    kPT  = qPT + 2 * QK_N;
    float*  Gpart = (float*)(wsb + 2 * QK_N * sizeof(float));
    wsb += 3 * U_N * sizeof(u16);                               // 37.75 MB region
    u16*    qP    = (u16*)wsb;
    u16*    xP    = (u16*)wsb;   wsb += 3 * QK_N * sizeof(u16); // 12.6 MB region
    u16*    kP    = (u16*)wsb;   wsb += 3 * QK_N * sizeof(u16); // 12.6 MB region
    u16*    GPT   = (u16*)wsb;
    u16*    WP    = (u16*)wsb;   wsb += 3 * G_N * sizeof(u16);  // 9.4 MB region
    double* tg    = (double*)wsb;                                // 8.4 MB region
    double* part  = tg;                                          // 1 MB   (alias)
    double* csC   = tg + (size_t)4 * 16 * L_;                    // 32 KB  (alias)
    double* csS   = csC + (size_t)B_ * L_;                       // 32 KB  (alias)

    k_prep    <<<dim3(L_ + 7680), 256, 0, stream>>>(x, Wq, Wk, xP, WP, tg);
    k_proj    <<<dim3(4, 32, 2),  256, 0, stream>>>(xP, WP, qraw, kraw);
    k_lnrope  <<<dim3(B_ * L_),   256, 0, stream>>>(qraw, kraw, tg, qg, qb, kg, kb, qP, kP);
    k_qkT     <<<dim3(32, 8, 8),  256, 0, stream>>>(qP, kP, qPT, kPT);
    k_gram    <<<dim3(8, 4, 12),  256, 0, stream>>>(qPT, kPT, Gpart);
    k_gsplitT <<<dim3(8, 8, 6),   256, 0, stream>>>(Gpart, GPT);
    k_u       <<<dim3(8, 16, 6),  256, 0, stream>>>(qP, kP, GPT, UP);
    k_scores  <<<dim3(16, 16, 6), 256, 0, stream>>>(qP, kP, UP, out);
    k_entmax  <<<dim3(3072),      256, 0, stream>>>(out + SLOT, 3 * B_ * L_, wC, wF, wS);
    k_colsum  <<<dim3(8, 16, 4),  256, 0, stream>>>(out, part);
    k_colred  <<<dim3(32),        256, 0, stream>>>(part, csC, csS);
    k_fin2    <<<dim3(B_ * L_),   256, 0, stream>>>(out, csC, csS);
}

// Round 9
// 445.641 us; speedup vs baseline: 1.0612x; 1.0612x over previous
//
#include <hip/hip_runtime.h>
#include <cstddef>
#include <math.h>

// ---------------- problem constants ----------------
#define B_   2
#define L_   2048
#define D_   512
#define E_   768
static const size_t LL   = (size_t)L_ * L_;
static const size_t SLOT = (size_t)B_ * LL;

#define QK_N  ((size_t)B_ * L_ * D_)       // 2097152
#define G1_N  ((size_t)512 * 512)          // 262144
#define G_N   ((size_t)6 * G1_N)           // 1572864
#define U_N   ((size_t)6 * L_ * D_)        // 6291456
#define X_N   ((size_t)4096 * 768)         // 3145728
#define W_N   ((size_t)512 * 768)          // 393216

typedef unsigned short u16;
typedef __attribute__((ext_vector_type(8))) _Float16 half8;  // 8 f16 (4 VGPR)
typedef __attribute__((ext_vector_type(4))) float f32x4;

// ---------------- f16x2 split of fp32, scaled residual ------------------------
// f = h0 + h1/4096 + r2, |r2| <= |f|*2^-24.
__device__ __forceinline__ void split2(float f, u16& h0, u16& h1) {
    _Float16 a = (_Float16)f;
    _Float16 b = (_Float16)((f - (float)a) * 4096.0f);
    h0 = __builtin_bit_cast(u16, a);
    h1 = __builtin_bit_cast(u16, b);
}

// ============ async global->LDS staging helpers ===============================
typedef const __attribute__((address_space(1))) void gas_void;
typedef __attribute__((address_space(3))) void las_void;

__device__ __forceinline__ void gload16(const u16* g, u16* l) {
    __builtin_amdgcn_global_load_lds((gas_void*)g, (las_void*)l, 16, 0, 0);
}

// ============ 128x64-tile MK PROM core (k_gram, k_u) — r3-proven ==============
// 4 waves as 2x2 of 64x32 quadrants, BK=32, fp64 promote per step. 24 KB LDS
// single-buffer, 2 barriers/step: high occupancy beats deeper scheduling here.
__device__ __forceinline__ void gemm12864p(const u16* __restrict__ Ap, size_t Aps, int lda,
                                           const u16* __restrict__ Bp, size_t Bps, int ldb,
                                           int K, int m0, int n0, int tid,
                                           double outv[4][2][4]) {
    __shared__ u16 SA[2][128][32], SB[2][64][32];    // 24 KB
    f32x4 accH[4][2], accM[4][2];
#pragma unroll
    for (int i = 0; i < 4; ++i)
#pragma unroll
        for (int j = 0; j < 2; ++j) {
            accH[i][j] = (f32x4){0.f, 0.f, 0.f, 0.f};
            accM[i][j] = (f32x4){0.f, 0.f, 0.f, 0.f};
        }
    double accD[4][2][4] = {};
    int lane = tid & 63, w = tid >> 6;
    int wm = (w & 1) << 6, wn = (w >> 1) << 5;       // 64x32 wave quadrant
    int fr = lane & 15, ko8 = lane >> 4;             // k-chunk 0..3

    int rbA0 = (w << 5), rbA1 = (w << 5) + 16;       // A: two 16-row slabs/wave
    int rowA0 = rbA0 + (lane >> 2), rowA1 = rbA1 + (lane >> 2);
    int chA0 = (lane & 3) ^ ((rowA0 >> 1) & 3);
    int chA1 = (lane & 3) ^ ((rowA1 >> 1) & 3);
    int rbB = (w << 4);                              // B: one 16-row slab/wave
    int rowB = rbB + (lane >> 2);
    int chB = (lane & 3) ^ ((rowB >> 1) & 3);

    int nstep = K >> 5;
    for (int s = 0; s < nstep; ++s) {
        int k0 = s << 5;
#pragma unroll
        for (int sp = 0; sp < 2; ++sp) {
            gload16(Ap + (size_t)sp * Aps + (size_t)(m0 + rowA0) * lda + k0 + (chA0 << 3),
                    &SA[sp][rbA0][0]);
            gload16(Ap + (size_t)sp * Aps + (size_t)(m0 + rowA1) * lda + k0 + (chA1 << 3),
                    &SA[sp][rbA1][0]);
            gload16(Bp + (size_t)sp * Bps + (size_t)(n0 + rowB) * ldb + k0 + (chB << 3),
                    &SB[sp][rbB][0]);
        }
        __syncthreads();                             // drains vmcnt -> LDS valid
        half8 a[4][2], b[2][2];
#pragma unroll
        for (int f = 0; f < 4; ++f) {
            int ra = wm + (f << 4) + fr;
            int ca = (ko8 ^ ((ra >> 1) & 3)) << 3;   // matching read-side swizzle
#pragma unroll
            for (int sp = 0; sp < 2; ++sp)
                a[f][sp] = *reinterpret_cast<const half8*>(&SA[sp][ra][ca]);
        }
#pragma unroll
        for (int f = 0; f < 2; ++f) {
            int rbn = wn + (f << 4) + fr;
            int cb = (ko8 ^ ((rbn >> 1) & 3)) << 3;
#pragma unroll
            for (int sp = 0; sp < 2; ++sp)
                b[f][sp] = *reinterpret_cast<const half8*>(&SB[sp][rbn][cb]);
        }
#pragma unroll
        for (int fi = 0; fi < 4; ++fi)
#pragma unroll
            for (int fj = 0; fj < 2; ++fj) {
                accH[fi][fj] = __builtin_amdgcn_mfma_f32_16x16x32_f16(a[fi][0], b[fj][0], accH[fi][fj], 0, 0, 0);
                accM[fi][fj] = __builtin_amdgcn_mfma_f32_16x16x32_f16(a[fi][0], b[fj][1], accM[fi][fj], 0, 0, 0);
                accM[fi][fj] = __builtin_amdgcn_mfma_f32_16x16x32_f16(a[fi][1], b[fj][0], accM[fi][fj], 0, 0, 0);
            }
        __syncthreads();                             // reads done before overwrite
#pragma unroll
        for (int fi = 0; fi < 4; ++fi)
#pragma unroll
            for (int fj = 0; fj < 2; ++fj) {
#pragma unroll
                for (int r = 0; r < 4; ++r) accD[fi][fj][r] += (double)accH[fi][fj][r];
                accH[fi][fj] = (f32x4){0.f, 0.f, 0.f, 0.f};
            }
    }
    const double S1 = 1.0 / 4096.0;
#pragma unroll
    for (int fi = 0; fi < 4; ++fi)
#pragma unroll
        for (int fj = 0; fj < 2; ++fj)
#pragma unroll
            for (int r = 0; r < 4; ++r)
                outv[fi][fj][r] = accD[fi][fj][r] + (double)accM[fi][fj][r] * S1;
}

// ============ counted-vmcnt 128x128 MK core (k_proj, k_scores) — r6-proven ====
// 256 thr / 4 waves / 64x64 per wave / 2 blocks/CU; LDS ping-pong + counted
// vmcnt with raw barriers. NEW r8: flat 64 KB SRAW (identical layout/addresses)
// so the epilogue can alias it as a fp32 transpose buffer for the symmetric-
// tile MIRROR write (C and S score matrices are symmetric -> compute lower
// triangle only, mirror the transpose). Main-loop numerics bit-identical.
__device__ __forceinline__ void gemm128cv(const u16* __restrict__ Ap, size_t Aps, int lda,
                                          const u16* __restrict__ Bp, size_t Bps, int ldb,
                                          int K, int m0, int n0, int tid,
                                          float* __restrict__ out, int ldo,
                                          bool mirror) {
    __shared__ u16 SRAW[32768];                      // 64 KB; A [0,16K) u16, B [16K,32K)
#define IDXA(buf, sp, row) (((((buf) * 2 + (sp)) * 128) + (row)) * 32)
#define IDXB(buf, sp, row) (16384 + ((((buf) * 2 + (sp)) * 128) + (row)) * 32)
    f32x4 accH[4][4], accM[4][4];
#pragma unroll
    for (int i = 0; i < 4; ++i)
#pragma unroll
        for (int j = 0; j < 4; ++j) {
            accH[i][j] = (f32x4){0.f, 0.f, 0.f, 0.f};
            accM[i][j] = (f32x4){0.f, 0.f, 0.f, 0.f};
        }
    int lane = tid & 63, w = tid >> 6;
    int wm = (w & 1) << 6, wn = (w >> 1) << 6;       // 64x64 wave quadrant
    int fr = lane & 15, ko8 = lane >> 4;             // k-chunk 0..3

    int rb0 = (w << 5), rb1 = rb0 + 16;              // two 16-row slabs per wave
    int row0 = rb0 + (lane >> 2), row1 = rb1 + (lane >> 2);
    int ch0 = (lane & 3) ^ ((row0 >> 1) & 3);        // inverse-swizzled source
    int ch1 = (lane & 3) ^ ((row1 >> 1) & 3);

#define STG128(buf, k0)                                                                   \
    {                                                                                     \
        _Pragma("unroll")                                                                 \
        for (int sp = 0; sp < 2; ++sp) {                                                  \
            gload16(Ap + (size_t)sp * Aps + (size_t)(m0 + row0) * lda + (k0) + (ch0 << 3),\
                    &SRAW[IDXA(buf, sp, rb0)]);                                           \
            gload16(Ap + (size_t)sp * Aps + (size_t)(m0 + row1) * lda + (k0) + (ch1 << 3),\
                    &SRAW[IDXA(buf, sp, rb1)]);                                           \
            gload16(Bp + (size_t)sp * Bps + (size_t)(n0 + row0) * ldb + (k0) + (ch0 << 3),\
                    &SRAW[IDXB(buf, sp, rb0)]);                                           \
            gload16(Bp + (size_t)sp * Bps + (size_t)(n0 + row1) * ldb + (k0) + (ch1 << 3),\
                    &SRAW[IDXB(buf, sp, rb1)]);                                           \
        }                                                                                 \
    }

    STG128(0, 0);                                    // 8 loads in flight; no drain
    int nstep = K >> 5;
    for (int s = 0; s < nstep; ++s) {
        int cur = s & 1;
        if (s + 1 < nstep) {
            STG128(cur ^ 1, (s + 1) << 5);           // 16 in flight
            asm volatile("s_waitcnt vmcnt(8)" ::: "memory");   // oldest 8 (cur) landed
        } else {
            asm volatile("s_waitcnt vmcnt(0)" ::: "memory");
        }
        __builtin_amdgcn_s_barrier();                // raw: no vmcnt drain
        asm volatile("" ::: "memory");               // pin ds_reads below barrier
        half8 a[4][2], b[4][2];
#pragma unroll
        for (int f = 0; f < 4; ++f) {
            int ra = wm + (f << 4) + fr;
            int rbn = wn + (f << 4) + fr;
            int ca = (ko8 ^ ((ra >> 1) & 3)) << 3;   // matching read-side swizzle
            int cb = (ko8 ^ ((rbn >> 1) & 3)) << 3;
#pragma unroll
            for (int sp = 0; sp < 2; ++sp) {
                a[f][sp] = *reinterpret_cast<const half8*>(&SRAW[IDXA(cur, sp, ra) + ca]);
                b[f][sp] = *reinterpret_cast<const half8*>(&SRAW[IDXB(cur, sp, rbn) + cb]);
            }
        }
        __builtin_amdgcn_s_setprio(1);
#pragma unroll
        for (int fi = 0; fi < 4; ++fi)
#pragma unroll
            for (int fj = 0; fj < 4; ++fj) {
                accH[fi][fj] = __builtin_amdgcn_mfma_f32_16x16x32_f16(a[fi][0], b[fj][0], accH[fi][fj], 0, 0, 0);
                accM[fi][fj] = __builtin_amdgcn_mfma_f32_16x16x32_f16(a[fi][0], b[fj][1], accM[fi][fj], 0, 0, 0);
                accM[fi][fj] = __builtin_amdgcn_mfma_f32_16x16x32_f16(a[fi][1], b[fj][0], accM[fi][fj], 0, 0, 0);
            }
        __builtin_amdgcn_s_setprio(0);
        asm volatile("s_waitcnt lgkmcnt(0)" ::: "memory");   // all ds_reads retired
        __builtin_amdgcn_s_barrier();                // reads done before overwrite
    }
#undef STG128
    const double S1 = 1.0 / 4096.0;
    int col = lane & 15, rbase = (lane >> 4) << 2;
#pragma unroll
    for (int fi = 0; fi < 4; ++fi)
#pragma unroll
        for (int fj = 0; fj < 4; ++fj)
#pragma unroll
            for (int r = 0; r < 4; ++r) {
                int mm = m0 + wm + (fi << 4) + rbase + r;
                int nn = n0 + wn + (fj << 4) + col;
                out[(size_t)mm * ldo + nn] =
                    (float)((double)accH[fi][fj][r] + (double)accM[fi][fj][r] * S1);
            }
    if (mirror) {
        // transpose 128x128 tile in two 64-row halves via LDS (129-float pitch:
        // conflict-free transposed reads), write to tile (J,I). All main-loop
        // LDS reads retired at the final barrier above -> SRAW reuse is safe.
        float* TF = (float*)SRAW;                    // 64 x 129 fp32 = 33 KB
        int hsel = wm >> 6;                          // which half this wave's rows are in
#pragma unroll
        for (int h = 0; h < 2; ++h) {
            __syncthreads();
            if (hsel == h) {
#pragma unroll
                for (int fi = 0; fi < 4; ++fi)
#pragma unroll
                    for (int fj = 0; fj < 4; ++fj)
#pragma unroll
                        for (int r = 0; r < 4; ++r) {
                            float v = (float)((double)accH[fi][fj][r] + (double)accM[fi][fj][r] * S1);
                            TF[((fi << 4) + rbase + r) * 129 + wn + (fj << 4) + col] = v;
                        }
            }
            __syncthreads();
#pragma unroll
            for (int i = 0; i < 32; ++i) {
                int idx = (i << 8) + tid;
                int tr = idx >> 6, tc = idx & 63;    // target row (128), col (64)
                out[(size_t)(n0 + tr) * ldo + m0 + (h << 6) + tc] = TF[tc * 129 + tr];
            }
        }
    }
#undef IDXA
#undef IDXB
}

// ============ prep: RoPE trig table + input f16x2 split (merged launch) =======
__global__ __launch_bounds__(256) void k_prep(const float* __restrict__ x,
                                              const float* __restrict__ Wq,
                                              const float* __restrict__ Wk,
                                              u16* __restrict__ xP,
                                              u16* __restrict__ WP,
                                              double* __restrict__ tg) {
    int bx = blockIdx.x;
    if (bx < L_) {
        int l = bx, j = threadIdx.x;
        double e = (double)j * (1.0 / 256.0);
        double inv = pow(10000.0, -e);
        double ang = (double)l * inv;
        tg[(size_t)l * 512 + j] = cos(ang);
        tg[(size_t)l * 512 + 256 + j] = sin(ang);
        return;
    }
    size_t gid = (size_t)(bx - L_) * 256 + threadIdx.x;
    const size_t XH = X_N / 2, WH = W_N / 2;
    const float* src; u16* dst; size_t pn, off;
    if (gid < XH)            { src = x  + 2 * gid;              dst = xP;            pn = X_N; off = 2 * gid; }
    else if (gid < XH + WH)  { size_t g = gid - XH;      src = Wq + 2 * g; dst = WP;            pn = W_N; off = 2 * g; }
    else                     { size_t g = gid - XH - WH; src = Wk + 2 * g; dst = WP + 2 * W_N;  pn = W_N; off = 2 * g; }
    float2 v = *reinterpret_cast<const float2*>(src);
    u16 a0, a1, b0, b1;
    split2(v.x, a0, a1);
    split2(v.y, b0, b1);
    *reinterpret_cast<unsigned*>(dst + off)      = (unsigned)a0 | ((unsigned)b0 << 16);
    *reinterpret_cast<unsigned*>(dst + pn + off) = (unsigned)a1 | ((unsigned)b1 << 16);
}

// ============ k_proj: 128-tile plane GEMM (fp32 H acc — O(1) magnitudes) ======
__global__ __launch_bounds__(256, 2) void k_proj(const u16* __restrict__ xP,
                                                 const u16* __restrict__ WP,
                                                 float* __restrict__ qraw,
                                                 float* __restrict__ kraw) {
    int z = blockIdx.z;
    float* out = z ? kraw : qraw;
    const u16* Bp = WP + (size_t)z * 2 * W_N;
    gemm128cv(xP, X_N, E_, Bp, W_N, E_, E_,
              blockIdx.y * 128, blockIdx.x * 128, threadIdx.x, out, D_, false);
}

// ============ LayerNorm + RoPE (fp64) -> f16x2 planes, q&k in parallel ========
__global__ __launch_bounds__(256) void k_lnrope(const float* __restrict__ qraw,
                                                const float* __restrict__ kraw,
                                                const double* __restrict__ tg,
                                                const float* __restrict__ qg, const float* __restrict__ qb,
                                                const float* __restrict__ kg, const float* __restrict__ kb,
                                                u16* __restrict__ qP, u16* __restrict__ kP) {
    int row = blockIdx.x;           // b*2048 + l
    int l = row & (L_ - 1);
    int tid = threadIdx.x;
    int half = tid >> 7, t = tid & 127;      // half 0 -> q, half 1 -> k
    __shared__ double nrow[2][D_];
    __shared__ double red[8];
    __shared__ double cs_[256], sn_[256];
    {
        int j = tid & 255;
        if (tid < 256) { cs_[j] = tg[(size_t)l * 512 + j]; sn_[j] = tg[(size_t)l * 512 + 256 + j]; }
    }
    const float* rp = (half ? kraw : qraw) + (size_t)row * D_;
    const float* g  = half ? kg : qg;
    const float* bt = half ? kb : qb;
    u16* P = half ? kP : qP;
    float4 v = reinterpret_cast<const float4*>(rp)[t];
    double vv[4] = {(double)v.x, (double)v.y, (double)v.z, (double)v.w};
    double s = vv[0] + vv[1] + vv[2] + vv[3];
    double s2 = vv[0]*vv[0] + vv[1]*vv[1] + vv[2]*vv[2] + vv[3]*vv[3];
    for (int off = 32; off; off >>= 1) { s += __shfl_xor(s, off); s2 += __shfl_xor(s2, off); }
    int wv = tid >> 6;                       // waves 0,1 -> half 0; 2,3 -> half 1
    if ((tid & 63) == 0) { red[wv * 2] = s; red[wv * 2 + 1] = s2; }
    __syncthreads();
    double mu  = (red[half * 4 + 0] + red[half * 4 + 2]) * (1.0 / D_);
    double var = (red[half * 4 + 1] + red[half * 4 + 3]) * (1.0 / D_) - mu * mu;
    double rs = rsqrt(var + 1e-5);
    int d0 = t * 4;
    double o[4];
#pragma unroll
    for (int c = 0; c < 4; ++c) {
        int d = d0 + c;
        o[c] = (vv[c] - mu) * rs * (double)g[d] + (double)bt[d];
    }
#pragma unroll
    for (int c = 0; c < 4; ++c) nrow[half][d0 + c] = o[c];
    __syncthreads();
    u16 h[2][4];
#pragma unroll
    for (int c = 0; c < 4; ++c) {
        int d = d0 + c;
        double rot = (d < 256) ? -nrow[half][d + 256] : nrow[half][d - 256];
        float ov = (float)(nrow[half][d] * cs_[d & 255] + rot * sn_[d & 255]);
        split2(ov, h[0][c], h[1][c]);
    }
    size_t off = (size_t)row * D_ + d0;
#pragma unroll
    for (int sp = 0; sp < 2; ++sp)
        *reinterpret_cast<ushort4*>(P + sp * QK_N + off) = make_ushort4(h[sp][0], h[sp][1], h[sp][2], h[sp][3]);
}

// ============ transpose q/k planes -> [d][l] layout (for MK-layout gram) ======
__global__ __launch_bounds__(256) void k_qkT(const u16* __restrict__ qP,
                                             const u16* __restrict__ kP,
                                             u16* __restrict__ qPT,
                                             u16* __restrict__ kPT) {
    __shared__ u16 T[64][72];
    int z = blockIdx.z;
    int b = z & 1, sp = (z >> 1) & 1, tn = z >> 2;
    const u16* src = (tn ? kP : qP) + (size_t)sp * QK_N + (size_t)b * L_ * D_;
    u16* dst       = (tn ? kPT : qPT) + (size_t)sp * QK_N + (size_t)b * D_ * L_;
    int l0 = blockIdx.x * 64, d0 = blockIdx.y * 64;
    int tid = threadIdx.x;
#pragma unroll
    for (int i = 0; i < 2; ++i) {
        int idx = tid + i * 256;
        int lr = idx >> 3, dc8 = (idx & 7) << 3;
        *reinterpret_cast<uint4*>(&T[lr][dc8]) =
            *reinterpret_cast<const uint4*>(&src[(size_t)(l0 + lr) * D_ + d0 + dc8]);
    }
    __syncthreads();
#pragma unroll
    for (int i = 0; i < 2; ++i) {
        int idx = tid + i * 256;
        int dr = idx >> 3, lc8 = (idx & 7) << 3;
        u16 tmp[8];
#pragma unroll
        for (int c = 0; c < 8; ++c) tmp[c] = T[lc8 + c][dr];
        *reinterpret_cast<uint4*>(&dst[(size_t)(d0 + dr) * L_ + l0 + lc8]) =
            *reinterpret_cast<const uint4*>(tmp);
    }
}

// ============ Gram split-K=2: transposed planes -> fp32 partials (PROM) =======
__global__ __launch_bounds__(256, 2) void k_gram(const u16* __restrict__ qPT,
                                                 const u16* __restrict__ kPT,
                                                 float* __restrict__ Gpart) {
    int zz = blockIdx.z, half = zz & 1, z = zz >> 1;
    int b = z / 3, m = z % 3;
    const u16* A  = ((m == 2) ? qPT : kPT) + (size_t)b * D_ * L_ + (size_t)half * (L_ / 2);
    const u16* Bp = ((m == 0) ? kPT : qPT) + (size_t)b * D_ * L_ + (size_t)half * (L_ / 2);
    int m0 = blockIdx.y * 128, n0 = blockIdx.x * 64;
    double ov[4][2][4];
    gemm12864p(A, QK_N, L_, Bp, QK_N, L_, L_ / 2, m0, n0, threadIdx.x, ov);
    float* Gg = Gpart + (size_t)half * G_N + (size_t)z * G1_N;
    int lane = threadIdx.x & 63, w = threadIdx.x >> 6;
    int wm = (w & 1) << 6, wn = (w >> 1) << 5;
    int col = lane & 15, rbase = (lane >> 4) << 2;
#pragma unroll
    for (int fi = 0; fi < 4; ++fi)
#pragma unroll
        for (int fj = 0; fj < 2; ++fj)
#pragma unroll
            for (int r = 0; r < 4; ++r) {
                int mm = m0 + wm + fi * 16 + rbase + r;
                int nn = n0 + wn + fj * 16 + col;
                Gg[(size_t)mm * 512 + nn] = (float)ov[fi][fj][r];
            }
}

// ============ sum partials + TRANSPOSE + split into G^T planes ================
__global__ __launch_bounds__(256) void k_gsplitT(const float* __restrict__ Gpart,
                                                 u16* __restrict__ GPT) {
    __shared__ float T[64][65];
    int z = blockIdx.z, d0 = blockIdx.y * 64, e0 = blockIdx.x * 64;
    const float* Ga = Gpart + (size_t)z * G1_N;
    const float* Gb = Ga + G_N;
    int tid = threadIdx.x;
#pragma unroll
    for (int i = 0; i < 16; ++i) {
        int idx = tid + i * 256;
        int r = idx >> 6, c = idx & 63;
        size_t o = (size_t)(d0 + r) * 512 + e0 + c;
        T[r][c] = Ga[o] + Gb[o];
    }
    __syncthreads();
    u16* Gz = GPT + (size_t)z * G1_N;
#pragma unroll
    for (int i = 0; i < 16; ++i) {
        int idx = tid + i * 256;
        int er = idx >> 6, dc = idx & 63;
        u16 h0, h1; split2(T[dc][er], h0, h1);
        size_t o = (size_t)(e0 + er) * 512 + d0 + dc;
        Gz[o] = h0; Gz[G_N + o] = h1;
    }
}

// ============ U = {q,q,k} @ G : planes -> U planes (PROM, 128x64 core) ========
__global__ __launch_bounds__(256, 2) void k_u(const u16* __restrict__ qP,
                                              const u16* __restrict__ kP,
                                              const u16* __restrict__ GPT,
                                              u16* __restrict__ UP) {
    int z = blockIdx.z, b = z / 3, m = z % 3;
    const u16* A  = ((m == 2) ? kP : qP) + (size_t)b * L_ * D_;
    const u16* Bp = GPT + (size_t)z * G1_N;
    int m0 = blockIdx.y * 128, n0 = blockIdx.x * 64;
    double ov[4][2][4];
    gemm12864p(A, QK_N, D_, Bp, G_N, 512, D_, m0, n0, threadIdx.x, ov);
    int lane = threadIdx.x & 63, w = threadIdx.x >> 6;
    int wm = (w & 1) << 6, wn = (w >> 1) << 5;
    int col = lane & 15, rbase = (lane >> 4) << 2;
#pragma unroll
    for (int fi = 0; fi < 4; ++fi)
#pragma unroll
        for (int fj = 0; fj < 2; ++fj)
#pragma unroll
            for (int r = 0; r < 4; ++r) {
                float uf = (float)ov[fi][fj][r];
                int mm = m0 + wm + fi * 16 + rbase + r;
                int nn = n0 + wn + fj * 16 + col;
                size_t off = (size_t)z * ((size_t)L_ * D_) + (size_t)mm * D_ + nn;
                u16 h0, h1; split2(uf, h0, h1);
                UP[off] = h0; UP[U_N + off] = h1;
            }
}

// ============ scores = U @ {q,k,k}^T — SYMMETRY-AWARE triangular grid =========
// C (m=0, U0=q·Gkk vs q) and S (m=2, U2=k·Gqq vs k) are symmetric: compute the
// 136 lower-triangle 128x128 tiles only; off-diagonal tiles mirror-write their
// transpose (LDS transpose, coalesced). F (m=1) stays full (256 tiles).
// Grid: 2 batches x (136 + 256 + 136) = 1056 blocks.
__global__ __launch_bounds__(256, 2) void k_scores(const u16* __restrict__ qP,
                                                   const u16* __restrict__ kP,
                                                   const u16* __restrict__ UP,
                                                   float* __restrict__ out) {
    int bid = blockIdx.x;
    int b = bid / 528, r = bid % 528;
    int m, I, J;
    if (r < 136) {
        m = 0;
        int t = r, i = 0;
        while ((i + 1) * (i + 2) / 2 <= t) ++i;
        I = i; J = t - i * (i + 1) / 2;
    } else if (r < 392) {
        m = 1; I = (r - 136) >> 4; J = (r - 136) & 15;
    } else {
        m = 2;
        int t = r - 392, i = 0;
        while ((i + 1) * (i + 2) / 2 <= t) ++i;
        I = i; J = t - i * (i + 1) / 2;
    }
    int z = b * 3 + m;
    const u16* A  = UP + (size_t)z * ((size_t)L_ * D_);
    const u16* Bp = ((m == 0) ? qP : kP) + (size_t)b * L_ * D_;
    float* Co = out + (size_t)(1 + m) * SLOT + (size_t)b * LL;
    bool mir = (m != 1) && (I != J);
    gemm128cv(A, U_N, D_, Bp, QK_N, D_, D_,
              I * 128, J * 128, threadIdx.x, Co, L_, mir);
}

// ============ entmax-1.5 (slots 1-3): fp32, 9 bisect + 3 Newton ===============
__global__ __launch_bounds__(256) void k_entmax(float* __restrict__ base, int nrows,
                                                const float* __restrict__ wC,
                                                const float* __restrict__ wF,
                                                const float* __restrict__ wS) {
    int tid = threadIdx.x;
    int lane = tid & 63;
    int r = blockIdx.x * 4 + (tid >> 6);
    if (r >= nrows) return;
    int m = r >> 12;                 // 4096 rows per matrix
    const float* wp = (m == 0) ? wC : (m == 1) ? wF : wS;
    float hw = (float)(1.0 / (1.0 + exp(-(double)wp[0])));   // 0.5 * w
    float* row = base + (size_t)r * L_;
    float v[32];
    float mx = -3.4e38f;
#pragma unroll
    for (int j = 0; j < 32; ++j) {
        v[j] = row[lane + (j << 6)];
        mx = fmaxf(mx, v[j]);
    }
    for (int off = 32; off; off >>= 1) mx = fmaxf(mx, __shfl_xor(mx, off));
    float z[32];
#pragma unroll
    for (int j = 0; j < 32; ++j) z[j] = hw * (v[j] - mx);
    float lo = -1.0f, hi = 0.0f;
    for (int it = 0; it < 9; ++it) {
        float tau = 0.5f * (lo + hi);
        float ssum = 0.0f;
#pragma unroll
        for (int j = 0; j < 32; ++j) {
            float t = fmaxf(z[j] - tau, 0.0f);
            ssum = fmaf(t, t, ssum);
        }
        for (int off = 32; off; off >>= 1) ssum += __shfl_xor(ssum, off);
        if (ssum >= 1.0f) lo = tau; else hi = tau;
    }
    float tau = lo;   // f(lo) >= 1; Newton on convex f approaches root from left
    for (int it = 0; it < 3; ++it) {
        float s1 = 0.0f, s2 = 0.0f;
#pragma unroll
        for (int j = 0; j < 32; ++j) {
            float t = fmaxf(z[j] - tau, 0.0f);
            s1 += t;
            s2 = fmaf(t, t, s2);
        }
        for (int off = 32; off; off >>= 1) { s1 += __shfl_xor(s1, off); s2 += __shfl_xor(s2, off); }
        float denom = 2.0f * s1;
        if (denom > 1e-30f) tau += fmaxf((s2 - 1.0f) / denom, 0.0f);
    }
#pragma unroll
    for (int j = 0; j < 32; ++j) {
        float t = fmaxf(z[j] - tau, 0.0f);
        row[lane + (j << 6)] = fminf(t * t, 1.0f - 1e-6f);
    }
}

// ============ column sums: partials (deterministic, parallel) =================
__global__ __launch_bounds__(256) void k_colsum(const float* __restrict__ out,
                                                double* __restrict__ part) {
    int bz = blockIdx.z, which = bz >> 1, b = bz & 1;
    const float* mat = out + (size_t)(which ? 3 : 1) * SLOT + (size_t)b * LL;
    int j = blockIdx.x * 256 + threadIdx.x;
    int r0 = blockIdx.y * 128;
    double s = 0.0;
#pragma unroll 8
    for (int r = 0; r < 128; ++r) s += (double)mat[(size_t)(r0 + r) * L_ + j];
    part[((size_t)bz * 16 + blockIdx.y) * L_ + j] = s;
}

__global__ __launch_bounds__(256) void k_colred(const double* __restrict__ part,
                                                double* __restrict__ csC,
                                                double* __restrict__ csS) {
    int g = blockIdx.x * 256 + threadIdx.x;   // 0..8191 = bz*2048 + j
    int bz = g >> 11, j = g & (L_ - 1);
    int which = bz >> 1, b = bz & 1;
    double s = 0.0;
#pragma unroll
    for (int c = 0; c < 16; ++c) s += part[((size_t)bz * 16 + c) * L_ + j];
    (which ? csS : csC)[b * L_ + j] = s;
}

// ============ fused finalize + entmax(H): one block per row ===================
__global__ __launch_bounds__(256) void k_fin2(float* __restrict__ out,
                                              const double* __restrict__ csC,
                                              const double* __restrict__ csS) {
    int row = blockIdx.x;               // b*2048 + i
    int i = row & (L_ - 1), b = row >> 11;
    size_t ro = (size_t)row * L_;
    float* H  = out + ro;
    float* pC = out + SLOT + ro;
    float* pF = out + 2 * SLOT + ro;
    float* pS = out + 3 * SLOT + ro;
    const double* cc = csC + b * L_;
    const double* cs = csS + b * L_;
    int tid = threadIdx.x, lane = tid & 63, wv = tid >> 6;
    __shared__ float red[4], red2[4];
    const double A1 = 1.0 - 2e-6;
    float h[8];
    float mx = -3.4e38f;
#pragma unroll
    for (int c = 0; c < 8; ++c) {
        int j = (c << 8) + tid;
        double cv = (double)pC[j] * rsqrt(cc[j] + 1e-6);
        double fv = (double)pF[j];
        double sv = (double)pS[j] * rsqrt(cs[j] + 1e-6);
        cv = fmax(A1 * cv + 1e-6, 1e-6);
        fv = fmax(A1 * fv + 1e-6, 1e-6);
        sv = fmax(A1 * sv + 1e-6, 1e-6);
        pC[j] = (float)cv; pF[j] = (float)fv; pS[j] = (float)sv;
        h[c] = (j == i) ? -1e9f : logf((float)(cv * fv * sv)) * (1.0f / 3.0f);
        mx = fmaxf(mx, h[c]);
    }
    for (int off = 32; off; off >>= 1) mx = fmaxf(mx, __shfl_xor(mx, off));
    if (lane == 0) red[wv] = mx;
    __syncthreads();
    mx = fmaxf(fmaxf(red[0], red[1]), fmaxf(red[2], red[3]));
    __syncthreads();
    float z[8];
#pragma unroll
    for (int c = 0; c < 8; ++c) z[c] = 0.5f * (h[c] - mx);
    float lo = -1.0f, hi = 0.0f;
    for (int it = 0; it < 9; ++it) {
        float tau = 0.5f * (lo + hi);
        float ssum = 0.0f;
#pragma unroll
        for (int c = 0; c < 8; ++c) {
            float t = fmaxf(z[c] - tau, 0.0f);
            ssum = fmaf(t, t, ssum);
        }
        for (int off = 32; off; off >>= 1) ssum += __shfl_xor(ssum, off);
        if (lane == 0) red[wv] = ssum;
        __syncthreads();
        ssum = red[0] + red[1] + red[2] + red[3];
        __syncthreads();
        if (ssum >= 1.0f) lo = tau; else hi = tau;
    }
    float tau = lo;
    for (int it = 0; it < 3; ++it) {
        float s1 = 0.0f, s2 = 0.0f;
#pragma unroll
        for (int c = 0; c < 8; ++c) {
            float t = fmaxf(z[c] - tau, 0.0f);
            s1 += t;
            s2 = fmaf(t, t, s2);
        }
        for (int off = 32; off; off >>= 1) { s1 += __shfl_xor(s1, off); s2 += __shfl_xor(s2, off); }
        if (lane == 0) { red[wv] = s1; red2[wv] = s2; }
        __syncthreads();
        s1 = red[0] + red[1] + red[2] + red[3];
        s2 = red2[0] + red2[1] + red2[2] + red2[3];
        __syncthreads();
        float denom = 2.0f * s1;
        if (denom > 1e-30f) tau += fmaxf((s2 - 1.0f) / denom, 0.0f);
    }
#pragma unroll
    for (int c = 0; c < 8; ++c) {
        float t = fmaxf(z[c] - tau, 0.0f);
        H[(c << 8) + tid] = t * t;
    }
}

// ============ launch ==========================================================
extern "C" void kernel_launch(void* const* d_in, const int* in_sizes, int n_in,
                              void* d_out, int out_size, void* d_ws, size_t ws_size,
                              hipStream_t stream) {
    const float* x  = (const float*)d_in[0];
    const float* Wq = (const float*)d_in[1];
    const float* Wk = (const float*)d_in[2];
    const float* qg = (const float*)d_in[3];
    const float* qb = (const float*)d_in[4];
    const float* kg = (const float*)d_in[5];
    const float* kb = (const float*)d_in[6];
    const float* wC = (const float*)d_in[7];
    const float* wF = (const float*)d_in[8];
    const float* wS = (const float*)d_in[9];
    float* out = (float*)d_out;

    // workspace: region boundaries identical to proven round-11..14 layout.
    char* wsb = (char*)d_ws;
    u16*    UP   = (u16*)wsb;
    float*  qraw = (float*)wsb;
    float*  kraw = qraw + QK_N;
    u16*    qPT  = (u16*)wsb;
    u16*    kPT  = qPT + 2 * QK_N;
    float*  Gpart = (float*)(wsb + 2 * QK_N * sizeof(float));
    wsb += 3 * U_N * sizeof(u16);                               // 37.75 MB region
    u16*    qP    = (u16*)wsb;
    u16*    xP    = (u16*)wsb;   wsb += 3 * QK_N * sizeof(u16); // 12.6 MB region
    u16*    kP    = (u16*)wsb;   wsb += 3 * QK_N * sizeof(u16); // 12.6 MB region
    u16*    GPT   = (u16*)wsb;
    u16*    WP    = (u16*)wsb;   wsb += 3 * G_N * sizeof(u16);  // 9.4 MB region
    double* tg    = (double*)wsb;                                // 8.4 MB region
    double* part  = tg;                                          // 1 MB   (alias)
    double* csC   = tg + (size_t)4 * 16 * L_;                    // 32 KB  (alias)
    double* csS   = csC + (size_t)B_ * L_;                       // 32 KB  (alias)

    k_prep    <<<dim3(L_ + 7680), 256, 0, stream>>>(x, Wq, Wk, xP, WP, tg);
    k_proj    <<<dim3(4, 32, 2),  256, 0, stream>>>(xP, WP, qraw, kraw);
    k_lnrope  <<<dim3(B_ * L_),   256, 0, stream>>>(qraw, kraw, tg, qg, qb, kg, kb, qP, kP);
    k_qkT     <<<dim3(32, 8, 8),  256, 0, stream>>>(qP, kP, qPT, kPT);
    k_gram    <<<dim3(8, 4, 12),  256, 0, stream>>>(qPT, kPT, Gpart);
    k_gsplitT <<<dim3(8, 8, 6),   256, 0, stream>>>(Gpart, GPT);
    k_u       <<<dim3(8, 16, 6),  256, 0, stream>>>(qP, kP, GPT, UP);
    k_scores  <<<dim3(1056),      256, 0, stream>>>(qP, kP, UP, out);
    k_entmax  <<<dim3(3072),      256, 0, stream>>>(out + SLOT, 3 * B_ * L_, wC, wF, wS);
    k_colsum  <<<dim3(8, 16, 4),  256, 0, stream>>>(out, part);
    k_colred  <<<dim3(32),        256, 0, stream>>>(part, csC, csS);
    k_fin2    <<<dim3(B_ * L_),   256, 0, stream>>>(out, csC, csS);
}